// Round 1
// baseline (305.166 us; speedup 1.0000x reference)
//
#include <hip/hip_runtime.h>
#include <math.h>

#define N_NODES 50000
#define N_PAD   50048
#define N_EDGES 800000
#define FEAT 128
#define K2 256
#define N_GRAPHS 512
#define N_CLASSES 10
#define BCAP 64          // bucket capacity (deg ~ Poisson(16); P(>64) ~ 0)
#define BROW 264         // sB row stride (shorts), pad for bank spread
#define OROW 72          // sOut row stride (shorts), 16B-aligned + bank spread
#define AGG_BLOCKS 2048  // persistent-wave grid for aggregation (8 blk/CU)

typedef __attribute__((ext_vector_type(8))) short short8;
typedef __attribute__((ext_vector_type(4))) float floatx4;

// ---------- bf16 helpers ----------
__device__ __forceinline__ float bflo(unsigned u) { return __uint_as_float(u << 16); }
__device__ __forceinline__ float bfhi(unsigned u) { return __uint_as_float(u & 0xffff0000u); }
__device__ __forceinline__ unsigned short f2bf(float f) {
    unsigned u = __float_as_uint(f);
    u = (u + 0x7fffu + ((u >> 16) & 1u)) >> 16;   // RNE
    return (unsigned short)u;
}
__device__ __forceinline__ unsigned pack2(float a, float b) {
    return (unsigned)f2bf(a) | ((unsigned)f2bf(b) << 16);
}

// ---------- bucket fill: single pass, one edge per thread ----------
__global__ __launch_bounds__(256) void fill_bucket(
    const int* __restrict__ src, const int* __restrict__ dst,
    int* __restrict__ cnt, unsigned short* __restrict__ bucket) {
    int e = blockIdx.x * 256 + threadIdx.x;   // grid covers exactly N_EDGES
    int d = dst[e];
    int p = atomicAdd(&cnt[d], 1);
    if (p < BCAP) bucket[(size_t)d * BCAP + p] = (unsigned short)src[e];
}

// ---------- setup: x -> bf16 into h-half of interleaved A0 | weights | goffs ----------
__global__ __launch_bounds__(256) void setup_kernel(
    const float* __restrict__ x, unsigned short* __restrict__ A,
    const float* __restrict__ wl1, const float* __restrict__ wr1,
    const float* __restrict__ wl23, const float* __restrict__ wr23,
    unsigned short* __restrict__ wt,
    const int* __restrict__ batch, int* __restrict__ goffs) {
    int b = blockIdx.x;
    if (b < 6250) {
        int idx = b * 256 + threadIdx.x;   // n*32 + f4
        if (idx < N_NODES * 32) {
            int n = idx >> 5, f4 = idx & 31;
            float4 v = ((const float4*)(x + (size_t)n * FEAT))[f4];
            uint2 o = make_uint2(pack2(v.x, v.y), pack2(v.z, v.w));
            *(uint2*)(A + (size_t)n * K2 + FEAT + f4 * 4) = o;
        }
    } else if (b < 6250 + 384) {
        int idx = (b - 6250) * 256 + threadIdx.x;  // 0..98303
        int layer = idx >> 15;
        int r = idx & 32767;
        int n = r >> 8, k = r & 255;
        const float* wl = (layer == 0) ? wl1 : wl23 + (size_t)(layer - 1) * FEAT * FEAT;
        const float* wr = (layer == 0) ? wr1 : wr23 + (size_t)(layer - 1) * FEAT * FEAT;
        float v = (k < FEAT) ? wl[k * FEAT + n] : wr[(k - FEAT) * FEAT + n];
        wt[idx] = f2bf(v);
    } else {
        int g = (b - 6250 - 384) * 256 + threadIdx.x;
        if (g > N_GRAPHS) return;
        int lo = 0, hi = N_NODES;
        while (lo < hi) {
            int mid = (lo + hi) >> 1;
            if (batch[mid] < g) lo = mid + 1; else hi = mid;
        }
        goffs[g] = lo;
    }
}

// ---------- aggregation: persistent waves, 1 node/wave/iter, pipelined ----------
// Reads X.h (stride K2 at +FEAT), writes X.agg (same row, other half): no hazard.
// Grid-stride over nodes; next node's cnt + full bucket line (128 B) prefetched
// before the current node's accumulate chain so the cnt->bucket dependency head
// hides under the current gathers.
__device__ __forceinline__ void acc8(float* acc, uint4 u) {
    acc[0] += bflo(u.x); acc[1] += bfhi(u.x);
    acc[2] += bflo(u.y); acc[3] += bfhi(u.y);
    acc[4] += bflo(u.z); acc[5] += bfhi(u.z);
    acc[6] += bflo(u.w); acc[7] += bfhi(u.w);
}

__global__ __launch_bounds__(256) void aggregate_bf16(
    const unsigned short* __restrict__ hin, const int* __restrict__ cnt,
    const unsigned short* __restrict__ bucket, unsigned short* __restrict__ aggout) {
    int lane = threadIdx.x & 63;
    int g = lane >> 4;        // edge slot within quad
    int l16 = lane & 15;      // 16 lanes x 16 B = 256 B row
    int wid = (blockIdx.x << 2) + (threadIdx.x >> 6);
    const int nw = gridDim.x << 2;

    int n = wid;
    if (n >= N_NODES) return;
    int deg = cnt[n];

    while (true) {
        const unsigned short* cp = bucket + (size_t)n * BCAP;
        int c = min(deg, BCAP);
        int nq = c >> 2;
        int rem = c & 3;

        // prefetch next node's cnt + whole bucket row (one 128 B line)
        int nn = n + nw;
        int dnext = 0;
        if (nn < N_NODES) {
            dnext = cnt[nn];
            unsigned short bpre = bucket[(size_t)nn * BCAP + lane];
            asm volatile("" :: "v"((int)bpre));   // keep the warming load live
        }

        float acc[8];
        #pragma unroll
        for (int i = 0; i < 8; ++i) acc[i] = 0.f;

        int i = 0;
        for (; i + 4 <= nq; i += 4) {
            int s0 = cp[i * 4 + g];
            int s1 = cp[i * 4 + 4 + g];
            int s2 = cp[i * 4 + 8 + g];
            int s3 = cp[i * 4 + 12 + g];
            uint4 u0 = *(const uint4*)(hin + (size_t)s0 * K2 + l16 * 8);
            uint4 u1 = *(const uint4*)(hin + (size_t)s1 * K2 + l16 * 8);
            uint4 u2 = *(const uint4*)(hin + (size_t)s2 * K2 + l16 * 8);
            uint4 u3 = *(const uint4*)(hin + (size_t)s3 * K2 + l16 * 8);
            acc8(acc, u0); acc8(acc, u1); acc8(acc, u2); acc8(acc, u3);
        }
        if (i + 2 <= nq) {
            int s0 = cp[i * 4 + g];
            int s1 = cp[i * 4 + 4 + g];
            uint4 u0 = *(const uint4*)(hin + (size_t)s0 * K2 + l16 * 8);
            uint4 u1 = *(const uint4*)(hin + (size_t)s1 * K2 + l16 * 8);
            acc8(acc, u0); acc8(acc, u1);
            i += 2;
        }
        if (i < nq) {
            int s0 = cp[i * 4 + g];
            uint4 u0 = *(const uint4*)(hin + (size_t)s0 * K2 + l16 * 8);
            acc8(acc, u0);
        }
        if (g < rem) {
            int s0 = cp[nq * 4 + g];
            uint4 u0 = *(const uint4*)(hin + (size_t)s0 * K2 + l16 * 8);
            acc8(acc, u0);
        }
        #pragma unroll
        for (int j = 0; j < 8; ++j) {
            acc[j] += __shfl_xor(acc[j], 16);
            acc[j] += __shfl_xor(acc[j], 32);
        }
        if (g == 0) {
            float inv = 1.0f / fmaxf((float)deg, 1.0f);
            uint4 o;
            o.x = pack2(acc[0] * inv, acc[1] * inv);
            o.y = pack2(acc[2] * inv, acc[3] * inv);
            o.z = pack2(acc[4] * inv, acc[5] * inv);
            o.w = pack2(acc[6] * inv, acc[7] * inv);
            *(uint4*)(aggout + (size_t)n * K2 + l16 * 8) = o;
        }
        if (nn >= N_NODES) break;
        n = nn;
        deg = dnext;
    }
}

// ---------- MFMA GEMM v7: Aout.h = relu(Ain.row @ Wt^T + b) ----------
// blockIdx (post-swizzle) = tileM*2 + nh: 128-row M-tile x 64-col N-half.
// Bijective XCD swizzle (nwg=782) co-locates the nh=0/1 pair (which share the
// same 64 KB A-panel) on one XCD so the pair-mate's A reads hit that XCD's L2.
// Per wave: 32 rows (2 bands) x 64 cols, acc = 32 VGPRs. B-half (64x256) staged
// in LDS once; A-frags preloaded in ONE 16-load batch; MFMA loop reads B from
// LDS. Output via per-wave LDS transpose -> coalesced dwordx4 stores.
// Layer 3: partial gate dot per n-half via 16-lane reduce + atomicAdd.
__global__ __launch_bounds__(256) void gemm_mfma(
    const unsigned short* __restrict__ Ain, unsigned short* __restrict__ Aout,
    const unsigned short* __restrict__ Wt, const float* __restrict__ bias,
    const float* __restrict__ gate_w, float* __restrict__ gate) {
    __shared__ unsigned short sB[64 * BROW];
    __shared__ unsigned short sOut[4][32 * OROW];
    int t = threadIdx.x;
    int wave = t >> 6, lane = t & 63;
    int q = lane >> 4, l16 = lane & 15;

    // bijective XCD swizzle (m204): nwg = 782 = 8*97 + 6
    const int nwg_q = 97, nwg_r = 6;
    int orig = blockIdx.x;
    int xcd = orig & 7, idx = orig >> 3;
    int wgid = (xcd < nwg_r) ? xcd * (nwg_q + 1) + idx
                             : nwg_r * (nwg_q + 1) + (xcd - nwg_r) * nwg_q + idx;
    int tileM = wgid >> 1;
    int nh = wgid & 1;
    int row0 = tileM * 128 + wave * 32;

    // preload A fragments: one 16-load batch (rows row0..row0+31, full K=256)
    const unsigned short* pa0 = Ain + (size_t)(row0 + l16) * K2 + q * 8;
    const unsigned short* pa1 = pa0 + 16 * K2;
    short8 a0[8], a1[8];
    #pragma unroll
    for (int ks = 0; ks < 8; ++ks) {
        a0[ks] = *(const short8*)(pa0 + ks * 32);
        a1[ks] = *(const short8*)(pa1 + ks * 32);
    }

    // stage B-half (output cols nh*64..nh*64+63) into padded LDS
    #pragma unroll
    for (int i = 0; i < 8; ++i) {
        int flat = i * 256 + t;            // 16B frag id, 0..2047
        int rw = flat >> 5, fr = flat & 31;
        uint4 v = *((const uint4*)(Wt + (size_t)(nh * 64 + rw) * K2) + fr);
        *(uint4*)(&sB[rw * BROW + fr * 8]) = v;
    }
    __syncthreads();

    floatx4 acc[2][4];
    #pragma unroll
    for (int i = 0; i < 2; ++i)
        #pragma unroll
        for (int j = 0; j < 4; ++j) acc[i][j] = (floatx4){0.f, 0.f, 0.f, 0.f};

    #pragma unroll
    for (int ks = 0; ks < 8; ++ks) {
        #pragma unroll
        for (int nb = 0; nb < 4; ++nb) {
            short8 b = *(const short8*)(&sB[(nb * 16 + l16) * BROW + ks * 32 + q * 8]);
            acc[0][nb] = __builtin_amdgcn_mfma_f32_16x16x32_bf16(a0[ks], b, acc[0][nb], 0, 0, 0);
            acc[1][nb] = __builtin_amdgcn_mfma_f32_16x16x32_bf16(a1[ks], b, acc[1][nb], 0, 0, 0);
        }
    }

    float bv[4], gwv[4];
    #pragma unroll
    for (int nb = 0; nb < 4; ++nb) bv[nb] = bias[nh * 64 + nb * 16 + l16];
    if (gate_w) {
        #pragma unroll
        for (int nb = 0; nb < 4; ++nb) gwv[nb] = gate_w[nh * 64 + nb * 16 + l16];
    }

    // epilogue: relu+bias -> per-wave LDS tile (rows 0..31 x cols 0..63)
    #pragma unroll
    for (int band = 0; band < 2; ++band) {
        #pragma unroll
        for (int r = 0; r < 4; ++r) {
            int lr = band * 16 + q * 4 + r;   // local row 0..31
            float gsum = 0.f;
            #pragma unroll
            for (int nb = 0; nb < 4; ++nb) {
                float v = fmaxf(acc[band][nb][r] + bv[nb], 0.f);
                sOut[wave][lr * OROW + nb * 16 + l16] = f2bf(v);
                if (gate_w) gsum += v * gwv[nb];
            }
            if (gate_w) {
                gsum += __shfl_xor(gsum, 1);
                gsum += __shfl_xor(gsum, 2);
                gsum += __shfl_xor(gsum, 4);
                gsum += __shfl_xor(gsum, 8);
                int m = row0 + lr;
                if (l16 == 0 && m < N_NODES) atomicAdd(&gate[m], gsum);
            }
        }
    }

    // coalesced store-back: lane covers (row r2, 32-short half h2)
    int r2 = lane >> 1, h2 = lane & 1;
    size_t gbase = (size_t)(row0 + r2) * K2 + FEAT + nh * 64 + h2 * 32;
    #pragma unroll
    for (int j = 0; j < 2; ++j) {
        uint4 v0 = *(uint4*)(&sOut[wave][r2 * OROW + h2 * 32 + j * 16]);
        uint4 v1 = *(uint4*)(&sOut[wave][r2 * OROW + h2 * 32 + j * 16 + 8]);
        *(uint4*)(Aout + gbase + j * 16) = v0;
        *(uint4*)(Aout + gbase + j * 16 + 8) = v1;
    }
}

// ---------- pooling + head: one block (256 thr) per graph ----------
// Computes its own segment max (gate is L2-hot, ~98 nodes/graph).
__global__ __launch_bounds__(256) void pool_head(
    const unsigned short* __restrict__ h, const float* __restrict__ gate,
    const int* __restrict__ goffs,
    const float* __restrict__ w1, const float* __restrict__ b1,
    const float* __restrict__ w2, const float* __restrict__ b2,
    float* __restrict__ out) {
    __shared__ float sred[4];
    __shared__ float facc[4][128];
    __shared__ float pv[128], qv[128], lg[N_CLASSES];
    int g = blockIdx.x;
    int s = goffs[g], e = goffs[g + 1];
    int t = threadIdx.x;
    int wave = t >> 6, lane = t & 63;

    if (s < e) {
        // segment max
        float mx = -INFINITY;
        for (int n = s + t; n < e; n += 256) mx = fmaxf(mx, gate[n]);
        #pragma unroll
        for (int off = 32; off; off >>= 1) mx = fmaxf(mx, __shfl_xor(mx, off));
        if (lane == 0) sred[wave] = mx;
        __syncthreads();
        float m = fmaxf(fmaxf(sred[0], sred[1]), fmaxf(sred[2], sred[3]));
        __syncthreads();
        // denominator
        float d = 0.f;
        for (int n = s + t; n < e; n += 256) d += __expf(gate[n] - m);
        #pragma unroll
        for (int off = 32; off; off >>= 1) d += __shfl_xor(d, off);
        if (lane == 0) sred[wave] = d;
        __syncthreads();
        float den = sred[0] + sred[1] + sred[2] + sred[3];
        // weighted feature sum
        float acc0 = 0.f, acc1 = 0.f;
        for (int n = s + wave; n < e; n += 4) {
            float gn = __expf(gate[n] - m);
            unsigned u = *(const unsigned*)(h + (size_t)n * K2 + lane * 2);
            acc0 += gn * bflo(u);
            acc1 += gn * bfhi(u);
        }
        facc[wave][lane * 2]     = acc0;
        facc[wave][lane * 2 + 1] = acc1;
        __syncthreads();
        if (t < 128) pv[t] = (facc[0][t] + facc[1][t] + facc[2][t] + facc[3][t]) / den;
    } else {
        if (t < 128) pv[t] = 0.f;
    }
    __syncthreads();

    if (t < 128) {
        float acc = b1[t];
        #pragma unroll 4
        for (int k = 0; k < 128; ++k) acc += pv[k] * w1[k * FEAT + t];
        qv[t] = fmaxf(acc, 0.f);
    }
    __syncthreads();
    if (t < N_CLASSES) {
        float a = b2[t];
        #pragma unroll 4
        for (int k = 0; k < 128; ++k) a += qv[k] * w2[k * N_CLASSES + t];
        lg[t] = a;
    }
    __syncthreads();
    if (t < N_CLASSES) {
        float m = -INFINITY;
        #pragma unroll
        for (int j = 0; j < N_CLASSES; ++j) m = fmaxf(m, lg[j]);
        float sum = 0.f;
        #pragma unroll
        for (int j = 0; j < N_CLASSES; ++j) sum += __expf(lg[j] - m);
        out[(size_t)g * N_CLASSES + t] = lg[t] - m - __logf(sum);
    }
}

// ---------- launch ----------
static inline size_t align256(size_t x) { return (x + 255) & ~(size_t)255; }

extern "C" void kernel_launch(void* const* d_in, const int* in_sizes, int n_in,
                              void* d_out, int out_size, void* d_ws, size_t ws_size,
                              hipStream_t stream) {
    const float* x        = (const float*)d_in[0];
    const int*   ei       = (const int*)d_in[1];
    const int*   batch    = (const int*)d_in[2];
    const float* conv1_wl = (const float*)d_in[4];
    const float* conv1_wr = (const float*)d_in[5];
    const float* conv1_b  = (const float*)d_in[6];
    const float* convs_wl = (const float*)d_in[7];
    const float* convs_wr = (const float*)d_in[8];
    const float* convs_b  = (const float*)d_in[9];
    const float* gate_w   = (const float*)d_in[10];
    const float* lin1_w   = (const float*)d_in[12];
    const float* lin1_b   = (const float*)d_in[13];
    const float* lin2_w   = (const float*)d_in[14];
    const float* lin2_b   = (const float*)d_in[15];
    float* out = (float*)d_out;

    const int* src = ei;
    const int* dst = ei + N_EDGES;

    char* w = (char*)d_ws;
    size_t off = 0;
    unsigned short* A0   = (unsigned short*)(w + off); off += align256((size_t)N_PAD * K2 * 2);
    unsigned short* A1   = (unsigned short*)(w + off); off += align256((size_t)N_PAD * K2 * 2);
    unsigned short* bkt  = (unsigned short*)(w + off); off += align256((size_t)N_NODES * BCAP * 2);
    unsigned short* wt   = (unsigned short*)(w + off); off += align256((size_t)3 * FEAT * K2 * 2);
    int*   i_goff = (int*)(w + off);   off += align256((size_t)(N_GRAPHS + 1) * 4);
    // zero region: cnt + gate contiguous
    char* zbase = w + off;
    int*   i_cnt  = (int*)(w + off);   off += align256((size_t)N_NODES * 4);
    float* f_gate = (float*)(w + off); off += align256((size_t)N_NODES * 4);
    size_t zbytes = (size_t)((w + off) - zbase);

    hipMemsetAsync(zbase, 0, zbytes, stream);

    fill_bucket<<<N_EDGES / 256, 256, 0, stream>>>(src, dst, i_cnt, bkt);
    setup_kernel<<<6250 + 384 + 3, 256, 0, stream>>>(
        x, A0, conv1_wl, conv1_wr, convs_wl, convs_wr, wt, batch, i_goff);

    const int GB = (N_PAD / 128) * 2;   // 782: 391 M-tiles x 2 N-halves

    // ping-pong: A0 -> A1 -> A0 -> A1
    aggregate_bf16<<<AGG_BLOCKS, 256, 0, stream>>>(A0 + FEAT, i_cnt, bkt, A0);
    gemm_mfma<<<GB, 256, 0, stream>>>(A0, A1, wt, conv1_b, nullptr, nullptr);
    aggregate_bf16<<<AGG_BLOCKS, 256, 0, stream>>>(A1 + FEAT, i_cnt, bkt, A1);
    gemm_mfma<<<GB, 256, 0, stream>>>(A1, A0, wt + FEAT * K2, convs_b, nullptr, nullptr);
    aggregate_bf16<<<AGG_BLOCKS, 256, 0, stream>>>(A0 + FEAT, i_cnt, bkt, A0);
    gemm_mfma<<<GB, 256, 0, stream>>>(A0, A1, wt + 2 * FEAT * K2, convs_b + FEAT,
                                      gate_w, f_gate);

    pool_head<<<N_GRAPHS, 256, 0, stream>>>(A1 + FEAT, f_gate, i_goff,
                                            lin1_w, lin1_b, lin2_w, lin2_b, out);
}

// Round 2
// 291.682 us; speedup vs baseline: 1.0462x; 1.0462x over previous
//
#include <hip/hip_runtime.h>
#include <math.h>

#define N_NODES 50000
#define N_PAD   50048
#define N_EDGES 800000
#define FEAT 128
#define K2 256
#define N_GRAPHS 512
#define N_CLASSES 10
#define BCAP 64          // bucket capacity (deg ~ Poisson(16); P(>64) ~ 0)
#define BROW 264         // sB row stride (shorts), pad for bank spread
#define OROW 72          // sOut row stride (shorts), 16B-aligned + bank spread
#define AGG_BLOCKS 2048  // persistent-wave grid for aggregation (8 blk/CU)

#define FILL_BLOCKS 1000 // 125 chunks x 8 XCD-ranges
#define FILL_ITER 25     // 125 * 25 * 256 = 800000 edges
#define RANGE_NODES 6250 // 50000 / 8
#define CNT_STRIDE 16    // one counter per 64B line (atomic de-serialization)
#define PREP_BLOCKS (FILL_BLOCKS + 6250 + 384 + 3)

typedef __attribute__((ext_vector_type(8))) short short8;
typedef __attribute__((ext_vector_type(4))) float floatx4;

// ---------- bf16 helpers ----------
__device__ __forceinline__ float bflo(unsigned u) { return __uint_as_float(u << 16); }
__device__ __forceinline__ float bfhi(unsigned u) { return __uint_as_float(u & 0xffff0000u); }
__device__ __forceinline__ unsigned short f2bf(float f) {
    unsigned u = __float_as_uint(f);
    u = (u + 0x7fffu + ((u >> 16) & 1u)) >> 16;   // RNE
    return (unsigned short)u;
}
__device__ __forceinline__ unsigned pack2(float a, float b) {
    return (unsigned)f2bf(a) | ((unsigned)f2bf(b) << 16);
}

// ---------- prep: bucket fill (XCD-range partitioned) + x->bf16 + weights + goffs ----------
// Fill blocks come FIRST so blockIdx%8 == dst-range == XCD (round-robin heuristic):
// all bucket/cnt writes for range r originate from one XCD -> lines stay in that
// L2, accumulate all 2B writes, write back once (kills the 27x write amplification).
// cnt is padded to 1 counter / 64B line so memory-side atomic RMWs pipeline
// across lines instead of serializing 16-deep on shared lines.
__global__ __launch_bounds__(256) void prep_kernel(
    const int* __restrict__ src, const int* __restrict__ dst,
    int* __restrict__ cnt, unsigned short* __restrict__ bucket,
    const float* __restrict__ x, unsigned short* __restrict__ A,
    const float* __restrict__ wl1, const float* __restrict__ wr1,
    const float* __restrict__ wl23, const float* __restrict__ wr23,
    unsigned short* __restrict__ wt,
    const int* __restrict__ batch, int* __restrict__ goffs) {
    int b = blockIdx.x, t = threadIdx.x;
    if (b < FILL_BLOCKS) {
        int chunk = b >> 3, r = b & 7;
        int lo = r * RANGE_NODES, hi = lo + RANGE_NODES;
        int base = chunk * (FILL_ITER * 256) + t;
        for (int i = 0; i < FILL_ITER; ++i) {
            int e = base + i * 256;          // coalesced dst scan
            int d = dst[e];
            if (d >= lo && d < hi) {
                int p = atomicAdd(&cnt[d << 4], 1);
                if (p < BCAP) bucket[(size_t)d * BCAP + p] = (unsigned short)src[e];
            }
        }
    } else if (b < FILL_BLOCKS + 6250) {
        int idx = (b - FILL_BLOCKS) * 256 + t;   // n*32 + f4
        if (idx < N_NODES * 32) {
            int n = idx >> 5, f4 = idx & 31;
            float4 v = ((const float4*)(x + (size_t)n * FEAT))[f4];
            uint2 o = make_uint2(pack2(v.x, v.y), pack2(v.z, v.w));
            *(uint2*)(A + (size_t)n * K2 + FEAT + f4 * 4) = o;
        }
    } else if (b < FILL_BLOCKS + 6250 + 384) {
        int idx = (b - FILL_BLOCKS - 6250) * 256 + t;  // 0..98303
        int layer = idx >> 15;
        int r = idx & 32767;
        int n = r >> 8, k = r & 255;
        const float* wl = (layer == 0) ? wl1 : wl23 + (size_t)(layer - 1) * FEAT * FEAT;
        const float* wr = (layer == 0) ? wr1 : wr23 + (size_t)(layer - 1) * FEAT * FEAT;
        float v = (k < FEAT) ? wl[k * FEAT + n] : wr[(k - FEAT) * FEAT + n];
        wt[idx] = f2bf(v);
    } else {
        int g = (b - FILL_BLOCKS - 6250 - 384) * 256 + t;
        if (g > N_GRAPHS) return;
        int lo = 0, hi = N_NODES;
        while (lo < hi) {
            int mid = (lo + hi) >> 1;
            if (batch[mid] < g) lo = mid + 1; else hi = mid;
        }
        goffs[g] = lo;
    }
}

// ---------- aggregation: persistent waves, 1 node/wave/iter, pipelined ----------
// Reads X.h (stride K2 at +FEAT), writes X.agg (same row, other half): no hazard.
// Grid-stride over nodes; next node's cnt + full bucket line (128 B) prefetched
// before the current node's accumulate chain so the cnt->bucket dependency head
// hides under the current gathers.
__device__ __forceinline__ void acc8(float* acc, uint4 u) {
    acc[0] += bflo(u.x); acc[1] += bfhi(u.x);
    acc[2] += bflo(u.y); acc[3] += bfhi(u.y);
    acc[4] += bflo(u.z); acc[5] += bfhi(u.z);
    acc[6] += bflo(u.w); acc[7] += bfhi(u.w);
}

__global__ __launch_bounds__(256) void aggregate_bf16(
    const unsigned short* __restrict__ hin, const int* __restrict__ cnt,
    const unsigned short* __restrict__ bucket, unsigned short* __restrict__ aggout) {
    int lane = threadIdx.x & 63;
    int g = lane >> 4;        // edge slot within quad
    int l16 = lane & 15;      // 16 lanes x 16 B = 256 B row
    int wid = (blockIdx.x << 2) + (threadIdx.x >> 6);
    const int nw = gridDim.x << 2;

    int n = wid;
    if (n >= N_NODES) return;
    int deg = cnt[n << 4];

    while (true) {
        const unsigned short* cp = bucket + (size_t)n * BCAP;
        int c = min(deg, BCAP);
        int nq = c >> 2;
        int rem = c & 3;

        // prefetch next node's cnt + whole bucket row (one 128 B line)
        int nn = n + nw;
        int dnext = 0;
        if (nn < N_NODES) {
            dnext = cnt[nn << 4];
            unsigned short bpre = bucket[(size_t)nn * BCAP + lane];
            asm volatile("" :: "v"((int)bpre));   // keep the warming load live
        }

        float acc[8];
        #pragma unroll
        for (int i = 0; i < 8; ++i) acc[i] = 0.f;

        int i = 0;
        for (; i + 4 <= nq; i += 4) {
            int s0 = cp[i * 4 + g];
            int s1 = cp[i * 4 + 4 + g];
            int s2 = cp[i * 4 + 8 + g];
            int s3 = cp[i * 4 + 12 + g];
            uint4 u0 = *(const uint4*)(hin + (size_t)s0 * K2 + l16 * 8);
            uint4 u1 = *(const uint4*)(hin + (size_t)s1 * K2 + l16 * 8);
            uint4 u2 = *(const uint4*)(hin + (size_t)s2 * K2 + l16 * 8);
            uint4 u3 = *(const uint4*)(hin + (size_t)s3 * K2 + l16 * 8);
            acc8(acc, u0); acc8(acc, u1); acc8(acc, u2); acc8(acc, u3);
        }
        if (i + 2 <= nq) {
            int s0 = cp[i * 4 + g];
            int s1 = cp[i * 4 + 4 + g];
            uint4 u0 = *(const uint4*)(hin + (size_t)s0 * K2 + l16 * 8);
            uint4 u1 = *(const uint4*)(hin + (size_t)s1 * K2 + l16 * 8);
            acc8(acc, u0); acc8(acc, u1);
            i += 2;
        }
        if (i < nq) {
            int s0 = cp[i * 4 + g];
            uint4 u0 = *(const uint4*)(hin + (size_t)s0 * K2 + l16 * 8);
            acc8(acc, u0);
        }
        if (g < rem) {
            int s0 = cp[nq * 4 + g];
            uint4 u0 = *(const uint4*)(hin + (size_t)s0 * K2 + l16 * 8);
            acc8(acc, u0);
        }
        #pragma unroll
        for (int j = 0; j < 8; ++j) {
            acc[j] += __shfl_xor(acc[j], 16);
            acc[j] += __shfl_xor(acc[j], 32);
        }
        if (g == 0) {
            float inv = 1.0f / fmaxf((float)deg, 1.0f);
            uint4 o;
            o.x = pack2(acc[0] * inv, acc[1] * inv);
            o.y = pack2(acc[2] * inv, acc[3] * inv);
            o.z = pack2(acc[4] * inv, acc[5] * inv);
            o.w = pack2(acc[6] * inv, acc[7] * inv);
            *(uint4*)(aggout + (size_t)n * K2 + l16 * 8) = o;
        }
        if (nn >= N_NODES) break;
        n = nn;
        deg = dnext;
    }
}

// ---------- MFMA GEMM v7: Aout.h = relu(Ain.row @ Wt^T + b) ----------
// blockIdx (post-swizzle) = tileM*2 + nh: 128-row M-tile x 64-col N-half.
// Bijective XCD swizzle (nwg=782) co-locates the nh=0/1 pair (which share the
// same 64 KB A-panel) on one XCD so the pair-mate's A reads hit that XCD's L2.
// Per wave: 32 rows (2 bands) x 64 cols, acc = 32 VGPRs. B-half (64x256) staged
// in LDS once; A-frags preloaded in ONE 16-load batch; MFMA loop reads B from
// LDS. Output via per-wave LDS transpose -> coalesced dwordx4 stores.
// Layer 3: partial gate dot per n-half via 16-lane reduce + atomicAdd.
__global__ __launch_bounds__(256) void gemm_mfma(
    const unsigned short* __restrict__ Ain, unsigned short* __restrict__ Aout,
    const unsigned short* __restrict__ Wt, const float* __restrict__ bias,
    const float* __restrict__ gate_w, float* __restrict__ gate) {
    __shared__ unsigned short sB[64 * BROW];
    __shared__ unsigned short sOut[4][32 * OROW];
    int t = threadIdx.x;
    int wave = t >> 6, lane = t & 63;
    int q = lane >> 4, l16 = lane & 15;

    // bijective XCD swizzle (m204): nwg = 782 = 8*97 + 6
    const int nwg_q = 97, nwg_r = 6;
    int orig = blockIdx.x;
    int xcd = orig & 7, idx = orig >> 3;
    int wgid = (xcd < nwg_r) ? xcd * (nwg_q + 1) + idx
                             : nwg_r * (nwg_q + 1) + (xcd - nwg_r) * nwg_q + idx;
    int tileM = wgid >> 1;
    int nh = wgid & 1;
    int row0 = tileM * 128 + wave * 32;

    // preload A fragments: one 16-load batch (rows row0..row0+31, full K=256)
    const unsigned short* pa0 = Ain + (size_t)(row0 + l16) * K2 + q * 8;
    const unsigned short* pa1 = pa0 + 16 * K2;
    short8 a0[8], a1[8];
    #pragma unroll
    for (int ks = 0; ks < 8; ++ks) {
        a0[ks] = *(const short8*)(pa0 + ks * 32);
        a1[ks] = *(const short8*)(pa1 + ks * 32);
    }

    // stage B-half (output cols nh*64..nh*64+63) into padded LDS
    #pragma unroll
    for (int i = 0; i < 8; ++i) {
        int flat = i * 256 + t;            // 16B frag id, 0..2047
        int rw = flat >> 5, fr = flat & 31;
        uint4 v = *((const uint4*)(Wt + (size_t)(nh * 64 + rw) * K2) + fr);
        *(uint4*)(&sB[rw * BROW + fr * 8]) = v;
    }
    __syncthreads();

    floatx4 acc[2][4];
    #pragma unroll
    for (int i = 0; i < 2; ++i)
        #pragma unroll
        for (int j = 0; j < 4; ++j) acc[i][j] = (floatx4){0.f, 0.f, 0.f, 0.f};

    #pragma unroll
    for (int ks = 0; ks < 8; ++ks) {
        #pragma unroll
        for (int nb = 0; nb < 4; ++nb) {
            short8 b = *(const short8*)(&sB[(nb * 16 + l16) * BROW + ks * 32 + q * 8]);
            acc[0][nb] = __builtin_amdgcn_mfma_f32_16x16x32_bf16(a0[ks], b, acc[0][nb], 0, 0, 0);
            acc[1][nb] = __builtin_amdgcn_mfma_f32_16x16x32_bf16(a1[ks], b, acc[1][nb], 0, 0, 0);
        }
    }

    float bv[4], gwv[4];
    #pragma unroll
    for (int nb = 0; nb < 4; ++nb) bv[nb] = bias[nh * 64 + nb * 16 + l16];
    if (gate_w) {
        #pragma unroll
        for (int nb = 0; nb < 4; ++nb) gwv[nb] = gate_w[nh * 64 + nb * 16 + l16];
    }

    // epilogue: relu+bias -> per-wave LDS tile (rows 0..31 x cols 0..63)
    #pragma unroll
    for (int band = 0; band < 2; ++band) {
        #pragma unroll
        for (int r = 0; r < 4; ++r) {
            int lr = band * 16 + q * 4 + r;   // local row 0..31
            float gsum = 0.f;
            #pragma unroll
            for (int nb = 0; nb < 4; ++nb) {
                float v = fmaxf(acc[band][nb][r] + bv[nb], 0.f);
                sOut[wave][lr * OROW + nb * 16 + l16] = f2bf(v);
                if (gate_w) gsum += v * gwv[nb];
            }
            if (gate_w) {
                gsum += __shfl_xor(gsum, 1);
                gsum += __shfl_xor(gsum, 2);
                gsum += __shfl_xor(gsum, 4);
                gsum += __shfl_xor(gsum, 8);
                int m = row0 + lr;
                if (l16 == 0 && m < N_NODES) atomicAdd(&gate[m], gsum);
            }
        }
    }

    // coalesced store-back: lane covers (row r2, 32-short half h2)
    int r2 = lane >> 1, h2 = lane & 1;
    size_t gbase = (size_t)(row0 + r2) * K2 + FEAT + nh * 64 + h2 * 32;
    #pragma unroll
    for (int j = 0; j < 2; ++j) {
        uint4 v0 = *(uint4*)(&sOut[wave][r2 * OROW + h2 * 32 + j * 16]);
        uint4 v1 = *(uint4*)(&sOut[wave][r2 * OROW + h2 * 32 + j * 16 + 8]);
        *(uint4*)(Aout + gbase + j * 16) = v0;
        *(uint4*)(Aout + gbase + j * 16 + 8) = v1;
    }
}

// ---------- pooling + head: one block (256 thr) per graph ----------
// Computes its own segment max (gate is L2-hot, ~98 nodes/graph).
__global__ __launch_bounds__(256) void pool_head(
    const unsigned short* __restrict__ h, const float* __restrict__ gate,
    const int* __restrict__ goffs,
    const float* __restrict__ w1, const float* __restrict__ b1,
    const float* __restrict__ w2, const float* __restrict__ b2,
    float* __restrict__ out) {
    __shared__ float sred[4];
    __shared__ float facc[4][128];
    __shared__ float pv[128], qv[128], lg[N_CLASSES];
    int g = blockIdx.x;
    int s = goffs[g], e = goffs[g + 1];
    int t = threadIdx.x;
    int wave = t >> 6, lane = t & 63;

    if (s < e) {
        // segment max
        float mx = -INFINITY;
        for (int n = s + t; n < e; n += 256) mx = fmaxf(mx, gate[n]);
        #pragma unroll
        for (int off = 32; off; off >>= 1) mx = fmaxf(mx, __shfl_xor(mx, off));
        if (lane == 0) sred[wave] = mx;
        __syncthreads();
        float m = fmaxf(fmaxf(sred[0], sred[1]), fmaxf(sred[2], sred[3]));
        __syncthreads();
        // denominator
        float d = 0.f;
        for (int n = s + t; n < e; n += 256) d += __expf(gate[n] - m);
        #pragma unroll
        for (int off = 32; off; off >>= 1) d += __shfl_xor(d, off);
        if (lane == 0) sred[wave] = d;
        __syncthreads();
        float den = sred[0] + sred[1] + sred[2] + sred[3];
        // weighted feature sum
        float acc0 = 0.f, acc1 = 0.f;
        for (int n = s + wave; n < e; n += 4) {
            float gn = __expf(gate[n] - m);
            unsigned u = *(const unsigned*)(h + (size_t)n * K2 + lane * 2);
            acc0 += gn * bflo(u);
            acc1 += gn * bfhi(u);
        }
        facc[wave][lane * 2]     = acc0;
        facc[wave][lane * 2 + 1] = acc1;
        __syncthreads();
        if (t < 128) pv[t] = (facc[0][t] + facc[1][t] + facc[2][t] + facc[3][t]) / den;
    } else {
        if (t < 128) pv[t] = 0.f;
    }
    __syncthreads();

    if (t < 128) {
        float acc = b1[t];
        #pragma unroll 4
        for (int k = 0; k < 128; ++k) acc += pv[k] * w1[k * FEAT + t];
        qv[t] = fmaxf(acc, 0.f);
    }
    __syncthreads();
    if (t < N_CLASSES) {
        float a = b2[t];
        #pragma unroll 4
        for (int k = 0; k < 128; ++k) a += qv[k] * w2[k * N_CLASSES + t];
        lg[t] = a;
    }
    __syncthreads();
    if (t < N_CLASSES) {
        float m = -INFINITY;
        #pragma unroll
        for (int j = 0; j < N_CLASSES; ++j) m = fmaxf(m, lg[j]);
        float sum = 0.f;
        #pragma unroll
        for (int j = 0; j < N_CLASSES; ++j) sum += __expf(lg[j] - m);
        out[(size_t)g * N_CLASSES + t] = lg[t] - m - __logf(sum);
    }
}

// ---------- launch ----------
static inline size_t align256(size_t x) { return (x + 255) & ~(size_t)255; }

extern "C" void kernel_launch(void* const* d_in, const int* in_sizes, int n_in,
                              void* d_out, int out_size, void* d_ws, size_t ws_size,
                              hipStream_t stream) {
    const float* x        = (const float*)d_in[0];
    const int*   ei       = (const int*)d_in[1];
    const int*   batch    = (const int*)d_in[2];
    const float* conv1_wl = (const float*)d_in[4];
    const float* conv1_wr = (const float*)d_in[5];
    const float* conv1_b  = (const float*)d_in[6];
    const float* convs_wl = (const float*)d_in[7];
    const float* convs_wr = (const float*)d_in[8];
    const float* convs_b  = (const float*)d_in[9];
    const float* gate_w   = (const float*)d_in[10];
    const float* lin1_w   = (const float*)d_in[12];
    const float* lin1_b   = (const float*)d_in[13];
    const float* lin2_w   = (const float*)d_in[14];
    const float* lin2_b   = (const float*)d_in[15];
    float* out = (float*)d_out;

    const int* src = ei;
    const int* dst = ei + N_EDGES;

    char* w = (char*)d_ws;
    size_t off = 0;
    unsigned short* A0   = (unsigned short*)(w + off); off += align256((size_t)N_PAD * K2 * 2);
    unsigned short* A1   = (unsigned short*)(w + off); off += align256((size_t)N_PAD * K2 * 2);
    unsigned short* bkt  = (unsigned short*)(w + off); off += align256((size_t)N_NODES * BCAP * 2);
    unsigned short* wt   = (unsigned short*)(w + off); off += align256((size_t)3 * FEAT * K2 * 2);
    int*   i_goff = (int*)(w + off);   off += align256((size_t)(N_GRAPHS + 1) * 4);
    // zero region: cnt (line-padded) + gate contiguous
    char* zbase = w + off;
    int*   i_cnt  = (int*)(w + off);   off += align256((size_t)N_NODES * CNT_STRIDE * 4);
    float* f_gate = (float*)(w + off); off += align256((size_t)N_NODES * 4);
    size_t zbytes = (size_t)((w + off) - zbase);

    hipMemsetAsync(zbase, 0, zbytes, stream);

    prep_kernel<<<PREP_BLOCKS, 256, 0, stream>>>(
        src, dst, i_cnt, bkt,
        x, A0, conv1_wl, conv1_wr, convs_wl, convs_wr, wt, batch, i_goff);

    const int GB = (N_PAD / 128) * 2;   // 782: 391 M-tiles x 2 N-halves

    // ping-pong: A0 -> A1 -> A0 -> A1
    aggregate_bf16<<<AGG_BLOCKS, 256, 0, stream>>>(A0 + FEAT, i_cnt, bkt, A0);
    gemm_mfma<<<GB, 256, 0, stream>>>(A0, A1, wt, conv1_b, nullptr, nullptr);
    aggregate_bf16<<<AGG_BLOCKS, 256, 0, stream>>>(A1 + FEAT, i_cnt, bkt, A1);
    gemm_mfma<<<GB, 256, 0, stream>>>(A1, A0, wt + FEAT * K2, convs_b, nullptr, nullptr);
    aggregate_bf16<<<AGG_BLOCKS, 256, 0, stream>>>(A0 + FEAT, i_cnt, bkt, A0);
    gemm_mfma<<<GB, 256, 0, stream>>>(A0, A1, wt + 2 * FEAT * K2, convs_b + FEAT,
                                      gate_w, f_gate);

    pool_head<<<N_GRAPHS, 256, 0, stream>>>(A1 + FEAT, f_gate, i_goff,
                                            lin1_w, lin1_b, lin2_w, lin2_b, out);
}